// Round 5
// baseline (80.532 us; speedup 1.0000x reference)
//
#include <hip/hip_runtime.h>
#include <hip/hip_bf16.h>

#define N_S     64
#define C_CH    128
#define L_SEQ   1600
#define H_HEADS 8
#define HD      16
#define SEG     50    // 32 segments * 50 = 1600
#define PADW    136   // weight LDS row pad (bf16 elems)
#define PADT    72    // x/y tile LDS row pad (bf16 elems)
#define SLABQ   804   // slab row stride in dwords (1608 ushorts; 804%32=4 -> <=2 lanes/bank)

typedef __attribute__((ext_vector_type(8))) short bf16x8;
typedef __attribute__((ext_vector_type(4))) float f32x4;

__device__ inline unsigned short f2bf(float f) {
  return __builtin_bit_cast(unsigned short, __float2bfloat16(f));
}
__device__ inline float bflo(unsigned int u) { return __builtin_bit_cast(float, u << 16); }
__device__ inline float bfhi(unsigned int u) { return __builtin_bit_cast(float, u & 0xffff0000u); }

// ---------------- K1: w2[n, c=16h+d, l] (bf16) = sum_c x[n,c,l]*Wa[16h+d][c] + ba ----------------
__global__ __launch_bounds__(256) void k_gemm1(const float* __restrict__ x,
                                               const float* __restrict__ Wa,
                                               const float* __restrict__ ba,
                                               unsigned short* __restrict__ w2) {
  __shared__ unsigned short was[128 * PADW];   // [o][c] rows
  __shared__ unsigned short xs[128 * PADT];    // [c][l] natural layout
  const int n = blockIdx.y;
  const int l0 = blockIdx.x * 64;
  const int t = threadIdx.x;
  const float* xn = x + (size_t)n * (C_CH * L_SEQ);

#pragma unroll
  for (int it = 0; it < 16; ++it) {
    int pos = it * 256 + t;
    int o = pos >> 5;
    int c4 = (pos & 31) << 2;
    float4 v = *reinterpret_cast<const float4*>(Wa + o * C_CH + c4);
    ushort4 u;
    u.x = f2bf(v.x); u.y = f2bf(v.y); u.z = f2bf(v.z); u.w = f2bf(v.w);
    *reinterpret_cast<ushort4*>(&was[o * PADW + c4]) = u;
  }
#pragma unroll
  for (int it = 0; it < 8; ++it) {
    int pos = it * 256 + t;
    int c = pos >> 4;
    int l4 = (pos & 15) << 2;
    float4 v = *reinterpret_cast<const float4*>(xn + (size_t)c * L_SEQ + l0 + l4);
    ushort4 u;
    u.x = f2bf(v.x); u.y = f2bf(v.y); u.z = f2bf(v.z); u.w = f2bf(v.w);
    *reinterpret_cast<ushort4*>(&xs[c * PADT + l4]) = u;
  }
  __syncthreads();

  const int wv = t >> 6;
  const int lane = t & 63;
  const int r16 = lane & 15;
  const int kg = lane >> 4;
  f32x4 acc[8];
#pragma unroll
  for (int ot = 0; ot < 8; ++ot) acc[ot] = (f32x4){0.f, 0.f, 0.f, 0.f};

#pragma unroll
  for (int ks = 0; ks < 4; ++ks) {
    bf16x8 a;
#pragma unroll
    for (int j = 0; j < 8; ++j)
      a[j] = (short)xs[(ks * 32 + kg * 8 + j) * PADT + wv * 16 + r16];
#pragma unroll
    for (int ot = 0; ot < 8; ++ot) {
      bf16x8 b = *reinterpret_cast<const bf16x8*>(&was[(ot * 16 + r16) * PADW + ks * 32 + kg * 8]);
      acc[ot] = __builtin_amdgcn_mfma_f32_16x16x32_bf16(a, b, acc[ot], 0, 0, 0);
    }
  }
#pragma unroll
  for (int ot = 0; ot < 8; ++ot) {
    float bav = ba[ot * 16 + r16];
    ushort4 u;
    u.x = f2bf(acc[ot][0] + bav);
    u.y = f2bf(acc[ot][1] + bav);
    u.z = f2bf(acc[ot][2] + bav);
    u.w = f2bf(acc[ot][3] + bav);
    size_t idx = (((size_t)n * H_HEADS + ot) * HD + r16) * L_SEQ + l0 + wv * 16 + kg * 4;
    *reinterpret_cast<ushort4*>(&w2[idx]) = u;
  }
}

// ---------------- K2: per-(n,h) scan; LDS-staged coalesced I/O + transpose-sum ----------------
__global__ __launch_bounds__(512) void k_scan(const unsigned short* __restrict__ w2,
                                              unsigned short* __restrict__ y2,
                                              const float* __restrict__ temp,
                                              const float* __restrict__ dbias) {
  __shared__ float big[16 * SLABQ];       // 51.5 KB: slab [16][2*SLABQ] bf16; aliased as cbuf
  __shared__ float tmp_l[L_SEQ];          // tmp, then raw e = exp(tmp - M)
  __shared__ float stot[32][17];
  __shared__ float pi_seg[32];
  __shared__ float red[16];
  float (*cbuf)[10][17] = (float(*)[10][17])big;   // sweep-1b scratch (slab is dead there)

  const int nh = blockIdx.x;
  const int h = nh & 7;
  const int t = threadIdx.x;
  const int d = t & 15;
  const int seg = t >> 4;
  const int l0 = seg * SEG;
  const float tscale = temp[h];
  const float db16 = 16.f * dbias[h];

  // ---- stage slab: coalesced uint4 global reads -> padded LDS rows ----
  const unsigned short* src = w2 + (size_t)nh * (HD * L_SEQ);
#pragma unroll
  for (int it = 0; it < 7; ++it) {
    int idx = it * 512 + t;               // uint4 index, 3200 total
    if (idx < 3200) {
      uint4 v = *reinterpret_cast<const uint4*>(src + (size_t)idx * 8);
      int row = idx / 200;                // = d
      int colq = idx - row * 200;         // uint4 within row
      *reinterpret_cast<uint4*>(&big[row * SLABQ + colq * 4]) = v;
    }
  }
  __syncthreads();

  // ---- extract this thread's 25 packed dwords from LDS ----
  unsigned int vp[25];
  const int rbase = d * SLABQ + seg * 25;
#pragma unroll
  for (int ii = 0; ii < 25; ++ii)
    vp[ii] = __builtin_bit_cast(unsigned int, big[rbase + ii]);

  // ---- sweep 1a: per-segment sum of w^2 per channel ----
  float tot = 0.f;
#pragma unroll
  for (int ii = 0; ii < 25; ++ii) {
    float a = bflo(vp[ii]), b = bfhi(vp[ii]);
    tot += a * a + b * b;
  }
  stot[seg][d] = tot;
  __syncthreads();                        // also: all slab reads done -> cbuf may overwrite
  float off = 0.f;
#pragma unroll
  for (int s = 0; s < 32; ++s) { float q = stot[s][d]; if (s < seg) off += q; }

  // ---- sweep 1b: cumsum of wsq -> c0 = wsq/denom; chunked LDS transpose-sum over d ----
  {
    float run = off;
    const int s2 = t / 10;                // 0..31 when t<320
    const int j2 = t - s2 * 10;
#pragma unroll
    for (int i0 = 0; i0 < SEG; i0 += 10) {
      float c0[10];
#pragma unroll
      for (int j = 0; j < 10; ++j) {
        int i = i0 + j;
        float v = (i & 1) ? bfhi(vp[i >> 1]) : bflo(vp[i >> 1]);
        float wsq = v * v;
        run += wsq;
        c0[j] = __fdividef(wsq, fmaxf(run, 1e-12f));
      }
      if (i0) __syncthreads();
#pragma unroll
      for (int j = 0; j < 10; ++j) cbuf[seg][j][d] = c0[j];
      __syncthreads();
      if (t < 320) {
        float a = 0.f;
#pragma unroll
        for (int dd = 0; dd < 16; ++dd) a += cbuf[s2][j2][dd];
        tmp_l[s2 * SEG + i0 + j2] = (a + db16) * tscale;
      }
    }
  }
  __syncthreads();

  // ---- softmax stats over tmp_l: M, then raw e, then S ----
  float m = -3.0e38f;
  for (int l = t; l < L_SEQ; l += 512) m = fmaxf(m, tmp_l[l]);
#pragma unroll
  for (int mask = 32; mask; mask >>= 1) m = fmaxf(m, __shfl_xor(m, mask));
  const int wid = t >> 6;
  if ((t & 63) == 0) red[wid] = m;
  __syncthreads();
  float M = red[0];
#pragma unroll
  for (int i2 = 1; i2 < 8; ++i2) M = fmaxf(M, red[i2]);
  float s = 0.f;
  for (int l = t; l < L_SEQ; l += 512) {
    float e = __expf(tmp_l[l] - M);
    tmp_l[l] = e;
    s += e;
  }
#pragma unroll
  for (int mask = 32; mask; mask >>= 1) s += __shfl_xor(s, mask);
  if ((t & 63) == 0) red[8 + wid] = s;
  __syncthreads();
  float S = 0.f;
#pragma unroll
  for (int i2 = 0; i2 < 8; ++i2) S += red[8 + i2];
  const float ninvS = -1.0f / S;
  const float epsS = 1e-8f * S;

  // ---- sweep 2a: per-segment totals of wsq*e (per d) and e ----
  float wp_tot = 0.f, pi_tot = 0.f;
#pragma unroll
  for (int ii = 0; ii < 25; ++ii) {
    float a = bflo(vp[ii]), b = bfhi(vp[ii]);
    float e0 = tmp_l[l0 + 2 * ii];
    float e1 = tmp_l[l0 + 2 * ii + 1];
    wp_tot += a * a * e0 + b * b * e1;
    pi_tot += e0 + e1;
  }
  stot[seg][d] = wp_tot;
  if (d == 0) pi_seg[seg] = pi_tot;
  __syncthreads();
  float wp_off = 0.f, pi_off = 0.f;
#pragma unroll
  for (int s2 = 0; s2 < 32; ++s2) {
    float vw = stot[s2][d];
    float vq = pi_seg[s2];
    if (s2 < seg) { wp_off += vw; pi_off += vq; }
  }

  // ---- sweep 2b: unnormalized running cumsums -> y = (w*e*attn)*(-invS), packed ----
  {
    float run_wp = wp_off, run_pi = pi_off;
#pragma unroll
    for (int ii = 0; ii < 25; ++ii) {
      float v0 = bflo(vp[ii]), v1 = bfhi(vp[ii]);
      float e0 = tmp_l[l0 + 2 * ii];
      run_pi += e0;
      run_wp += v0 * v0 * e0;
      float dn0 = run_pi + epsS;
      float y0 = (v0 * e0) * __fdividef(dn0, dn0 + run_wp) * ninvS;
      float e1 = tmp_l[l0 + 2 * ii + 1];
      run_pi += e1;
      run_wp += v1 * v1 * e1;
      float dn1 = run_pi + epsS;
      float y1 = (v1 * e1) * __fdividef(dn1, dn1 + run_wp) * ninvS;
      vp[ii] = (unsigned int)f2bf(y0) | ((unsigned int)f2bf(y1) << 16);
    }
  }

  // ---- stage y through LDS slab, then coalesced uint4 global stores ----
  __syncthreads();                        // cbuf/tmp readers done; slab reusable
#pragma unroll
  for (int ii = 0; ii < 25; ++ii)
    big[rbase + ii] = __builtin_bit_cast(float, vp[ii]);
  __syncthreads();
  unsigned short* dst = y2 + (size_t)nh * (HD * L_SEQ);
#pragma unroll
  for (int it = 0; it < 7; ++it) {
    int idx = it * 512 + t;
    if (idx < 3200) {
      int row = idx / 200;
      int colq = idx - row * 200;
      uint4 v = *reinterpret_cast<const uint4*>(&big[row * SLABQ + colq * 4]);
      *reinterpret_cast<uint4*>(dst + (size_t)idx * 8) = v;
    }
  }
}

// ---------------- K3: out = relu(Wp . y + bp + x)  (bf16 MFMA, y2 d-major) ----------------
__global__ __launch_bounds__(256) void k_gemm2(const unsigned short* __restrict__ y2,
                                               const float* __restrict__ Wp,
                                               const float* __restrict__ bp,
                                               const float* __restrict__ x,
                                               float* __restrict__ out) {
  __shared__ unsigned short wps[128 * PADW];   // [o][c] rows
  __shared__ unsigned short ys[128 * PADT];    // [c][l] natural layout
  const int n = blockIdx.y;
  const int l0 = blockIdx.x * 64;
  const int t = threadIdx.x;

#pragma unroll
  for (int it = 0; it < 16; ++it) {
    int pos = it * 256 + t;
    int o = pos >> 5;
    int c4 = (pos & 31) << 2;
    float4 v = *reinterpret_cast<const float4*>(Wp + o * C_CH + c4);
    ushort4 u;
    u.x = f2bf(v.x); u.y = f2bf(v.y); u.z = f2bf(v.z); u.w = f2bf(v.w);
    *reinterpret_cast<ushort4*>(&wps[o * PADW + c4]) = u;
  }
#pragma unroll
  for (int it = 0; it < 4; ++it) {
    int pos = it * 256 + t;          // 0..1023
    int c = pos >> 3;
    int l8 = (pos & 7) << 3;
    uint4 v = *reinterpret_cast<const uint4*>(y2 + ((size_t)n * C_CH + c) * L_SEQ + l0 + l8);
    *reinterpret_cast<uint4*>(&ys[c * PADT + l8]) = v;
  }
  __syncthreads();

  const int wv = t >> 6;
  const int lane = t & 63;
  const int r16 = lane & 15;
  const int kg = lane >> 4;
  f32x4 acc[8];
#pragma unroll
  for (int ot = 0; ot < 8; ++ot) acc[ot] = (f32x4){0.f, 0.f, 0.f, 0.f};

#pragma unroll
  for (int ks = 0; ks < 4; ++ks) {
    bf16x8 b;
#pragma unroll
    for (int j = 0; j < 8; ++j)
      b[j] = (short)ys[(ks * 32 + kg * 8 + j) * PADT + wv * 16 + r16];
#pragma unroll
    for (int ot = 0; ot < 8; ++ot) {
      bf16x8 a = *reinterpret_cast<const bf16x8*>(&wps[(ot * 16 + r16) * PADW + ks * 32 + kg * 8]);
      acc[ot] = __builtin_amdgcn_mfma_f32_16x16x32_bf16(a, b, acc[ot], 0, 0, 0);
    }
  }
  const int gl = l0 + wv * 16 + r16;
#pragma unroll
  for (int ot = 0; ot < 8; ++ot) {
#pragma unroll
    for (int i = 0; i < 4; ++i) {
      int o = ot * 16 + kg * 4 + i;
      size_t idx = (size_t)n * (C_CH * L_SEQ) + (size_t)o * L_SEQ + gl;
      float r = acc[ot][i] + bp[o] + x[idx];
      out[idx] = fmaxf(r, 0.f);
    }
  }
}

extern "C" void kernel_launch(void* const* d_in, const int* in_sizes, int n_in,
                              void* d_out, int out_size, void* d_ws, size_t ws_size,
                              hipStream_t stream) {
  const float* x     = (const float*)d_in[0];
  const float* Wa    = (const float*)d_in[1];
  const float* ba    = (const float*)d_in[2];
  const float* Wp    = (const float*)d_in[3];
  const float* bp    = (const float*)d_in[4];
  const float* temp  = (const float*)d_in[5];
  const float* dbias = (const float*)d_in[6];
  float* out = (float*)d_out;

  unsigned short* w2 = (unsigned short*)d_ws;                       // 26.2 MB
  unsigned short* y2 = w2 + (size_t)N_S * H_HEADS * L_SEQ * HD;     // 26.2 MB

  k_gemm1<<<dim3(L_SEQ / 64, N_S), 256, 0, stream>>>(x, Wa, ba, w2);
  k_scan<<<N_S * H_HEADS, 512, 0, stream>>>(w2, y2, temp, dbias);
  k_gemm2<<<dim3(L_SEQ / 64, N_S), 256, 0, stream>>>(y2, Wp, bp, x, out);
}

// Round 6
// 77.045 us; speedup vs baseline: 1.0453x; 1.0453x over previous
//
#include <hip/hip_runtime.h>
#include <hip/hip_bf16.h>

#define N_S     64
#define C_CH    128
#define L_SEQ   1600
#define H_HEADS 8
#define HD      16
#define SEG     50    // 32 segments * 50 = 1600
#define PADW    136   // weight LDS row pad (bf16 elems)
#define PADT    72    // x/y tile LDS row pad (bf16 elems)

typedef __attribute__((ext_vector_type(8))) short bf16x8;
typedef __attribute__((ext_vector_type(4))) float f32x4;

__device__ inline unsigned short f2bf(float f) {
  return __builtin_bit_cast(unsigned short, __float2bfloat16(f));
}
__device__ inline float bflo(unsigned int u) { return __builtin_bit_cast(float, u << 16); }
__device__ inline float bfhi(unsigned int u) { return __builtin_bit_cast(float, u & 0xffff0000u); }

// ---------------- K1: w2[n, c=16h+d, l] (bf16) = sum_c x[n,c,l]*Wa[16h+d][c] + ba ----------------
__global__ __launch_bounds__(256) void k_gemm1(const float* __restrict__ x,
                                               const float* __restrict__ Wa,
                                               const float* __restrict__ ba,
                                               unsigned short* __restrict__ w2) {
  __shared__ unsigned short was[128 * PADW];   // [o][c] rows
  __shared__ unsigned short xs[128 * PADT];    // [c][l] natural layout
  const int n = blockIdx.y;
  const int l0 = blockIdx.x * 64;
  const int t = threadIdx.x;
  const float* xn = x + (size_t)n * (C_CH * L_SEQ);

#pragma unroll
  for (int it = 0; it < 16; ++it) {
    int pos = it * 256 + t;
    int o = pos >> 5;
    int c4 = (pos & 31) << 2;
    float4 v = *reinterpret_cast<const float4*>(Wa + o * C_CH + c4);
    ushort4 u;
    u.x = f2bf(v.x); u.y = f2bf(v.y); u.z = f2bf(v.z); u.w = f2bf(v.w);
    *reinterpret_cast<ushort4*>(&was[o * PADW + c4]) = u;
  }
#pragma unroll
  for (int it = 0; it < 8; ++it) {
    int pos = it * 256 + t;
    int c = pos >> 4;
    int l4 = (pos & 15) << 2;
    float4 v = *reinterpret_cast<const float4*>(xn + (size_t)c * L_SEQ + l0 + l4);
    ushort4 u;
    u.x = f2bf(v.x); u.y = f2bf(v.y); u.z = f2bf(v.z); u.w = f2bf(v.w);
    *reinterpret_cast<ushort4*>(&xs[c * PADT + l4]) = u;
  }
  __syncthreads();

  const int wv = t >> 6;
  const int lane = t & 63;
  const int r16 = lane & 15;
  const int kg = lane >> 4;
  f32x4 acc[8];
#pragma unroll
  for (int ot = 0; ot < 8; ++ot) acc[ot] = (f32x4){0.f, 0.f, 0.f, 0.f};

#pragma unroll
  for (int ks = 0; ks < 4; ++ks) {
    bf16x8 a;
#pragma unroll
    for (int j = 0; j < 8; ++j)
      a[j] = (short)xs[(ks * 32 + kg * 8 + j) * PADT + wv * 16 + r16];
#pragma unroll
    for (int ot = 0; ot < 8; ++ot) {
      bf16x8 b = *reinterpret_cast<const bf16x8*>(&was[(ot * 16 + r16) * PADW + ks * 32 + kg * 8]);
      acc[ot] = __builtin_amdgcn_mfma_f32_16x16x32_bf16(a, b, acc[ot], 0, 0, 0);
    }
  }
#pragma unroll
  for (int ot = 0; ot < 8; ++ot) {
    float bav = ba[ot * 16 + r16];
    ushort4 u;
    u.x = f2bf(acc[ot][0] + bav);
    u.y = f2bf(acc[ot][1] + bav);
    u.z = f2bf(acc[ot][2] + bav);
    u.w = f2bf(acc[ot][3] + bav);
    size_t idx = (((size_t)n * H_HEADS + ot) * HD + r16) * L_SEQ + l0 + wv * 16 + kg * 4;
    *reinterpret_cast<ushort4*>(&w2[idx]) = u;
  }
}

// ---------------- K2: per-(n,h) scan; per-wave transpose, analytic softmax max ----------------
__global__ __launch_bounds__(512) void k_scan(const unsigned short* __restrict__ w2,
                                              unsigned short* __restrict__ y2,
                                              const float* __restrict__ temp,
                                              const float* __restrict__ dbias) {
  __shared__ float tmp_l[L_SEQ];          // e = exp(tmp - M), unnormalized
  __shared__ float cbufw[8 * 680];        // per-wave scratch: [wave][4*10*17]
  __shared__ float stot[32][17];
  __shared__ float pi_seg[32];
  __shared__ float red[8];

  const int nh = blockIdx.x;
  const int h = nh & 7;
  const int t = threadIdx.x;
  const int d = t & 15;
  const int seg = t >> 4;
  const int wv = t >> 6;
  const int lane = t & 63;
  const int sl = lane >> 4;               // local seg within wave (0..3)
  const int l0 = seg * SEG;
  const size_t base = ((size_t)nh * HD + d) * L_SEQ + l0;
  const float tscale = temp[h];
  const float db16 = 16.f * dbias[h];
  // Sigma_d wsq/denom is in (0,16], ==16 at l=0 -> exact-at-l0 upper bound on tmp.
  const float M = fmaxf((16.f + db16) * tscale, db16 * tscale);

  // ---- load this thread's contiguous 50-elem bf16 slice (25 packed dwords) ----
  unsigned int vp[25];
#pragma unroll
  for (int ii = 0; ii < 25; ++ii)
    vp[ii] = *reinterpret_cast<const unsigned int*>(w2 + base + 2 * ii);

  // ---- sweep 1a: per-segment sum of w^2 per channel ----
  float tot = 0.f;
#pragma unroll
  for (int ii = 0; ii < 25; ++ii) {
    float a = bflo(vp[ii]), b = bfhi(vp[ii]);
    tot += a * a + b * b;
  }
  stot[seg][d] = tot;
  __syncthreads();                        // barrier 1
  float off = 0.f;
#pragma unroll
  for (int s = 0; s < 32; ++s) { float q = stot[s][d]; if (s < seg) off += q; }

  // ---- sweep 1b: cumsum -> c0 = wsq/denom; per-wave transpose-sum; fused exp ----
  float* cw = &cbufw[wv * 680];
  const int rsl = lane / 10;              // reader mapping (valid for lane<40)
  const int rj = lane - rsl * 10;
  float run = off;
  float sAcc = 0.f;
#pragma unroll
  for (int i0 = 0; i0 < SEG; i0 += 10) {
#pragma unroll
    for (int j = 0; j < 10; ++j) {
      int i = i0 + j;
      float v = (i & 1) ? bfhi(vp[i >> 1]) : bflo(vp[i >> 1]);
      float wsq = v * v;
      run += wsq;
      cw[(sl * 10 + j) * 17 + d] = __fdividef(wsq, fmaxf(run, 1e-12f));
    }
    __builtin_amdgcn_wave_barrier();      // keep compiler from moving reads above writes
    if (lane < 40) {
      float a = 0.f;
#pragma unroll
      for (int dd = 0; dd < 16; ++dd) a += cw[(rsl * 10 + rj) * 17 + dd];
      float e = __expf((a + db16) * tscale - M);
      tmp_l[(4 * wv + rsl) * SEG + i0 + rj] = e;
      sAcc += e;
    }
    __builtin_amdgcn_wave_barrier();      // reads done before next chunk overwrites
  }
  // block-reduce S (writer lanes hold partials; idle lanes contribute 0)
#pragma unroll
  for (int mask = 32; mask; mask >>= 1) sAcc += __shfl_xor(sAcc, mask);
  if (lane == 0) red[wv] = sAcc;
  __syncthreads();                        // barrier 2: red + tmp_l visible; stot reusable
  float S = 0.f;
#pragma unroll
  for (int i2 = 0; i2 < 8; ++i2) S += red[i2];
  const float ninvS = -1.0f / S;
  const float epsS = 1e-8f * S;

  // ---- sweep 2a: per-segment totals of wsq*e (per d) and e ----
  float wp_tot = 0.f, pi_tot = 0.f;
#pragma unroll
  for (int ii = 0; ii < 25; ++ii) {
    float a = bflo(vp[ii]), b = bfhi(vp[ii]);
    float e0 = tmp_l[l0 + 2 * ii];
    float e1 = tmp_l[l0 + 2 * ii + 1];
    wp_tot += a * a * e0 + b * b * e1;
    pi_tot += e0 + e1;
  }
  stot[seg][d] = wp_tot;
  if (d == 0) pi_seg[seg] = pi_tot;
  __syncthreads();                        // barrier 3
  float wp_off = 0.f, pi_off = 0.f;
#pragma unroll
  for (int s2 = 0; s2 < 32; ++s2) {
    float vw = stot[s2][d];
    float vq = pi_seg[s2];
    if (s2 < seg) { wp_off += vw; pi_off += vq; }
  }

  // ---- sweep 2b: unnormalized running cumsums -> y = (w*e*attn)*(-invS), packed ----
  {
    float run_wp = wp_off, run_pi = pi_off;
#pragma unroll
    for (int ii = 0; ii < 25; ++ii) {
      float v0 = bflo(vp[ii]), v1 = bfhi(vp[ii]);
      float e0 = tmp_l[l0 + 2 * ii];
      run_pi += e0;
      run_wp += v0 * v0 * e0;
      float dn0 = run_pi + epsS;
      float y0 = (v0 * e0) * __fdividef(dn0, dn0 + run_wp) * ninvS;
      float e1 = tmp_l[l0 + 2 * ii + 1];
      run_pi += e1;
      run_wp += v1 * v1 * e1;
      float dn1 = run_pi + epsS;
      float y1 = (v1 * e1) * __fdividef(dn1, dn1 + run_wp) * ninvS;
      vp[ii] = (unsigned int)f2bf(y0) | ((unsigned int)f2bf(y1) << 16);
    }
  }
#pragma unroll
  for (int ii = 0; ii < 25; ++ii)
    *reinterpret_cast<unsigned int*>(y2 + base + 2 * ii) = vp[ii];
}

// ---------------- K3: out = relu(Wp . y + bp + x)  (bf16 MFMA, y2 d-major) ----------------
__global__ __launch_bounds__(256) void k_gemm2(const unsigned short* __restrict__ y2,
                                               const float* __restrict__ Wp,
                                               const float* __restrict__ bp,
                                               const float* __restrict__ x,
                                               float* __restrict__ out) {
  __shared__ unsigned short wps[128 * PADW];   // [o][c] rows
  __shared__ unsigned short ys[128 * PADT];    // [c][l] natural layout
  const int n = blockIdx.y;
  const int l0 = blockIdx.x * 64;
  const int t = threadIdx.x;

#pragma unroll
  for (int it = 0; it < 16; ++it) {
    int pos = it * 256 + t;
    int o = pos >> 5;
    int c4 = (pos & 31) << 2;
    float4 v = *reinterpret_cast<const float4*>(Wp + o * C_CH + c4);
    ushort4 u;
    u.x = f2bf(v.x); u.y = f2bf(v.y); u.z = f2bf(v.z); u.w = f2bf(v.w);
    *reinterpret_cast<ushort4*>(&wps[o * PADW + c4]) = u;
  }
#pragma unroll
  for (int it = 0; it < 4; ++it) {
    int pos = it * 256 + t;          // 0..1023
    int c = pos >> 3;
    int l8 = (pos & 7) << 3;
    uint4 v = *reinterpret_cast<const uint4*>(y2 + ((size_t)n * C_CH + c) * L_SEQ + l0 + l8);
    *reinterpret_cast<uint4*>(&ys[c * PADT + l8]) = v;
  }
  __syncthreads();

  const int wv = t >> 6;
  const int lane = t & 63;
  const int r16 = lane & 15;
  const int kg = lane >> 4;
  f32x4 acc[8];
#pragma unroll
  for (int ot = 0; ot < 8; ++ot) acc[ot] = (f32x4){0.f, 0.f, 0.f, 0.f};

#pragma unroll
  for (int ks = 0; ks < 4; ++ks) {
    bf16x8 b;
#pragma unroll
    for (int j = 0; j < 8; ++j)
      b[j] = (short)ys[(ks * 32 + kg * 8 + j) * PADT + wv * 16 + r16];
#pragma unroll
    for (int ot = 0; ot < 8; ++ot) {
      bf16x8 a = *reinterpret_cast<const bf16x8*>(&wps[(ot * 16 + r16) * PADW + ks * 32 + kg * 8]);
      acc[ot] = __builtin_amdgcn_mfma_f32_16x16x32_bf16(a, b, acc[ot], 0, 0, 0);
    }
  }
  const int gl = l0 + wv * 16 + r16;
#pragma unroll
  for (int ot = 0; ot < 8; ++ot) {
#pragma unroll
    for (int i = 0; i < 4; ++i) {
      int o = ot * 16 + kg * 4 + i;
      size_t idx = (size_t)n * (C_CH * L_SEQ) + (size_t)o * L_SEQ + gl;
      float r = acc[ot][i] + bp[o] + x[idx];
      out[idx] = fmaxf(r, 0.f);
    }
  }
}

extern "C" void kernel_launch(void* const* d_in, const int* in_sizes, int n_in,
                              void* d_out, int out_size, void* d_ws, size_t ws_size,
                              hipStream_t stream) {
  const float* x     = (const float*)d_in[0];
  const float* Wa    = (const float*)d_in[1];
  const float* ba    = (const float*)d_in[2];
  const float* Wp    = (const float*)d_in[3];
  const float* bp    = (const float*)d_in[4];
  const float* temp  = (const float*)d_in[5];
  const float* dbias = (const float*)d_in[6];
  float* out = (float*)d_out;

  unsigned short* w2 = (unsigned short*)d_ws;                       // 26.2 MB
  unsigned short* y2 = w2 + (size_t)N_S * H_HEADS * L_SEQ * HD;     // 26.2 MB

  k_gemm1<<<dim3(L_SEQ / 64, N_S), 256, 0, stream>>>(x, Wa, ba, w2);
  k_scan<<<N_S * H_HEADS, 512, 0, stream>>>(w2, y2, temp, dbias);
  k_gemm2<<<dim3(L_SEQ / 64, N_S), 256, 0, stream>>>(y2, Wp, bp, x, out);
}